// Round 1
// baseline (34903.372 us; speedup 1.0000x reference)
//
#include <hip/hip_runtime.h>

#define TT 512
#define BB 64
#define HH 1024
#define EE 512
#define VV 50000

typedef __attribute__((ext_vector_type(8))) short bf16x8;
typedef __attribute__((ext_vector_type(4))) float f32x4;

__device__ inline float b2f(unsigned short b){
  unsigned int u = ((unsigned int)b) << 16;
  float f; __builtin_memcpy(&f, &u, 4); return f;
}
__device__ inline unsigned short f2b(float f){
  unsigned int u; __builtin_memcpy(&u, &f, 4);
  unsigned int r = (u + 0x7FFFu + ((u >> 16) & 1u)) >> 16;
  return (unsigned short)r;
}
__device__ inline float sigmoidf_(float x){ return 1.0f / (1.0f + __expf(-x)); }
__device__ inline float tanhf_(float x){ float e = __expf(2.0f * x); return 1.0f - 2.0f / (e + 1.0f); }

// ---------------- cast fp32 -> bf16 (vector x4) ----------------
__global__ void cast_f2b(const float* __restrict__ src, unsigned short* __restrict__ dst, long n){
  long i = ((long)blockIdx.x * blockDim.x + threadIdx.x) * 4;
  long stride = (long)gridDim.x * blockDim.x * 4;
  for (; i + 3 < n; i += stride){
    float4 v = *reinterpret_cast<const float4*>(src + i);
    ushort4 r;
    r.x = f2b(v.x); r.y = f2b(v.y); r.z = f2b(v.z); r.w = f2b(v.w);
    *reinterpret_cast<ushort4*>(dst + i) = r;
  }
}

// ---------------- per-layer init: h->bf16 buffer, c->fp32 state, pooled=0 ----------------
__global__ void init_layer(const float* __restrict__ h0, const float* __restrict__ c0,
                           unsigned short* __restrict__ hbuf, float* __restrict__ c_state,
                           float* __restrict__ pooled){
  int i = blockIdx.x * blockDim.x + threadIdx.x;   // grid covers B*H = 65536
  hbuf[i] = f2b(h0[i]);
  c_state[i] = c0[i];
  if (pooled) pooled[i] = 0.0f;
}

// ---------------- save final h (bf16) to fp32 output ----------------
__global__ void save_h(const unsigned short* __restrict__ h, float* __restrict__ out){
  int i = blockIdx.x * blockDim.x + threadIdx.x;
  out[i] = b2f(h[i]);
}

// ---------------- one LSTM timestep ----------------
// grid = 64 blocks (16 hidden units each), block = 256 threads (4 waves = 4 batch-blocks of 16)
// gates[b, g*H + j] = sum_k x[b,k] * Wx[g*H+j, k]  +  sum_k h[b,k] * Wh[g*H+j, k]
// MFMA 16x16x32 bf16: A lane: A[lane&15, (lane>>4)*8 + j]; B lane: B[(lane>>4)*8 + j, lane&15];
// D lane: D[(lane>>4)*4 + i, lane&15]
template<int LAYER>
__global__ __launch_bounds__(256) void lstm_step(
    const unsigned short* __restrict__ xsrc,   // L0: emb_bf [V,E]; L1: y0 + t*B*H
    const int* __restrict__ idx,               // L0: inputs + t*B ; L1: unused
    const unsigned short* __restrict__ hprev,  // [B,H] bf16
    unsigned short* __restrict__ hout,         // [B,H] bf16
    const unsigned short* __restrict__ Wx,     // [4H, KX] bf16
    const unsigned short* __restrict__ Wh,     // [4H, H] bf16
    float* __restrict__ c_state,               // [B,H] fp32 (lives in d_out cn region)
    float* __restrict__ pooled)                // [B,H] fp32 (layer1 only)
{
  constexpr int KX = (LAYER == 0) ? EE : HH;
  const int lane = threadIdx.x & 63;
  const int wid  = threadIdx.x >> 6;
  const int l16  = lane & 15;
  const int kq   = (lane >> 4) << 3;       // 0,8,16,24
  const int j0   = blockIdx.x << 4;        // hidden-unit slice base
  const int m    = (wid << 4) + l16;       // batch row for A-operand loads
  const int jr   = j0 + l16;               // hidden unit (B-operand row within gate / out col)

  const unsigned short* ax;
  if (LAYER == 0) ax = xsrc + (size_t)idx[m] * EE;
  else            ax = xsrc + (size_t)m * HH;
  const unsigned short* ah = hprev + (size_t)m * HH;

  const unsigned short* bx = Wx + (size_t)jr * KX;   // gate-i row; gate g at +g*H*KX
  const unsigned short* bh = Wh + (size_t)jr * HH;

  f32x4 acc0 = {0.f,0.f,0.f,0.f};
  f32x4 acc1 = {0.f,0.f,0.f,0.f};
  f32x4 acc2 = {0.f,0.f,0.f,0.f};
  f32x4 acc3 = {0.f,0.f,0.f,0.f};

  // x-projection part (folded in): K = KX
  #pragma unroll 2
  for (int k = 0; k < KX; k += 32){
    bf16x8 a  = *(const bf16x8*)(ax + k + kq);
    bf16x8 b0 = *(const bf16x8*)(bx + k + kq);
    bf16x8 b1 = *(const bf16x8*)(bx + (size_t)1*HH*KX + k + kq);
    bf16x8 b2 = *(const bf16x8*)(bx + (size_t)2*HH*KX + k + kq);
    bf16x8 b3 = *(const bf16x8*)(bx + (size_t)3*HH*KX + k + kq);
    acc0 = __builtin_amdgcn_mfma_f32_16x16x32_bf16(a, b0, acc0, 0, 0, 0);
    acc1 = __builtin_amdgcn_mfma_f32_16x16x32_bf16(a, b1, acc1, 0, 0, 0);
    acc2 = __builtin_amdgcn_mfma_f32_16x16x32_bf16(a, b2, acc2, 0, 0, 0);
    acc3 = __builtin_amdgcn_mfma_f32_16x16x32_bf16(a, b3, acc3, 0, 0, 0);
  }
  // recurrent part: K = H
  #pragma unroll 2
  for (int k = 0; k < HH; k += 32){
    bf16x8 a  = *(const bf16x8*)(ah + k + kq);
    bf16x8 b0 = *(const bf16x8*)(bh + k + kq);
    bf16x8 b1 = *(const bf16x8*)(bh + (size_t)1*HH*HH + k + kq);
    bf16x8 b2 = *(const bf16x8*)(bh + (size_t)2*HH*HH + k + kq);
    bf16x8 b3 = *(const bf16x8*)(bh + (size_t)3*HH*HH + k + kq);
    acc0 = __builtin_amdgcn_mfma_f32_16x16x32_bf16(a, b0, acc0, 0, 0, 0);
    acc1 = __builtin_amdgcn_mfma_f32_16x16x32_bf16(a, b1, acc1, 0, 0, 0);
    acc2 = __builtin_amdgcn_mfma_f32_16x16x32_bf16(a, b2, acc2, 0, 0, 0);
    acc3 = __builtin_amdgcn_mfma_f32_16x16x32_bf16(a, b3, acc3, 0, 0, 0);
  }

  // elementwise LSTM cell update; lane holds gates i,f,g,o for 4 (m, jr) pairs
  const int mrow0 = (wid << 4) + ((lane >> 4) << 2);
  #pragma unroll
  for (int i = 0; i < 4; ++i){
    int mi = mrow0 + i;
    size_t off = (size_t)mi * HH + jr;
    float gi = sigmoidf_(acc0[i]);
    float gf = sigmoidf_(acc1[i]);
    float gg = tanhf_(acc2[i]);
    float go = sigmoidf_(acc3[i]);
    float cnew = gf * c_state[off] + gi * gg;
    float hnew = go * tanhf_(cnew);
    c_state[off] = cnew;
    hout[off] = f2b(hnew);
    if (LAYER == 1) pooled[off] += hnew;
  }
}

// ---------------- decode: out[b] = dot(pooled[b], decW)/T + decb ----------------
__global__ void decode_k(const float* __restrict__ pooled, const float* __restrict__ decW,
                         const float* __restrict__ decb, float* __restrict__ out){
  __shared__ float red[256];
  int b = blockIdx.x;
  float s = 0.0f;
  for (int j = threadIdx.x; j < HH; j += 256) s += pooled[(size_t)b * HH + j] * decW[j];
  red[threadIdx.x] = s;
  __syncthreads();
  for (int w = 128; w > 0; w >>= 1){
    if (threadIdx.x < w) red[threadIdx.x] += red[threadIdx.x + w];
    __syncthreads();
  }
  if (threadIdx.x == 0) out[b] = red[0] * (1.0f / (float)TT) + decb[0];
}

extern "C" void kernel_launch(void* const* d_in, const int* in_sizes, int n_in,
                              void* d_out, int out_size, void* d_ws, size_t ws_size,
                              hipStream_t stream){
  const int*   inputs = (const int*)d_in[0];
  const float* h0     = (const float*)d_in[1];
  const float* c0     = (const float*)d_in[2];
  const float* emb    = (const float*)d_in[3];
  const float* Wih0   = (const float*)d_in[4];
  const float* Whh0   = (const float*)d_in[5];
  const float* Wih1   = (const float*)d_in[6];
  const float* Whh1   = (const float*)d_in[7];
  const float* decW   = (const float*)d_in[8];
  const float* decb   = (const float*)d_in[9];

  char* ws = (char*)d_ws;
  size_t off = 0;
  auto alloc = [&](size_t bytes) -> void* {
    void* p = ws + off;
    off += (bytes + 255) & ~(size_t)255;
    return p;
  };
  unsigned short* emb_bf  = (unsigned short*)alloc((size_t)VV * EE * 2);
  unsigned short* Wih0_bf = (unsigned short*)alloc((size_t)4 * HH * EE * 2);
  unsigned short* Whh0_bf = (unsigned short*)alloc((size_t)4 * HH * HH * 2);
  unsigned short* Wih1_bf = (unsigned short*)alloc((size_t)4 * HH * HH * 2);
  unsigned short* Whh1_bf = (unsigned short*)alloc((size_t)4 * HH * HH * 2);
  unsigned short* y0      = (unsigned short*)alloc((size_t)TT * BB * HH * 2);
  unsigned short* h0bf    = (unsigned short*)alloc((size_t)BB * HH * 2);
  unsigned short* ping0   = (unsigned short*)alloc((size_t)BB * HH * 2);
  unsigned short* ping1   = (unsigned short*)alloc((size_t)BB * HH * 2);
  float*          pooled  = (float*)alloc((size_t)BB * HH * 4);

  float* out = (float*)d_out;            // decoded [B,1]
  float* hn  = out + BB;                 // hn [2,B,H]
  float* cn  = out + BB + 2 * BB * HH;   // cn [2,B,H] — used as live fp32 c state

  // cast weights + embedding to bf16
  cast_f2b<<<1024, 256, 0, stream>>>(emb,  emb_bf,  (long)VV * EE);
  cast_f2b<<<256,  256, 0, stream>>>(Wih0, Wih0_bf, (long)4 * HH * EE);
  cast_f2b<<<256,  256, 0, stream>>>(Whh0, Whh0_bf, (long)4 * HH * HH);
  cast_f2b<<<256,  256, 0, stream>>>(Wih1, Wih1_bf, (long)4 * HH * HH);
  cast_f2b<<<256,  256, 0, stream>>>(Whh1, Whh1_bf, (long)4 * HH * HH);

  // ---------------- layer 0 ----------------
  init_layer<<<256, 256, 0, stream>>>(h0, c0, h0bf, cn, nullptr);
  for (int t = 0; t < TT; ++t){
    const unsigned short* hp = (t == 0) ? h0bf : y0 + (size_t)(t - 1) * BB * HH;
    unsigned short* ho = y0 + (size_t)t * BB * HH;
    lstm_step<0><<<64, 256, 0, stream>>>(emb_bf, inputs + t * BB, hp, ho,
                                         Wih0_bf, Whh0_bf, cn, nullptr);
  }
  save_h<<<256, 256, 0, stream>>>(y0 + (size_t)(TT - 1) * BB * HH, hn);

  // ---------------- layer 1 ----------------
  init_layer<<<256, 256, 0, stream>>>(h0 + (size_t)BB * HH, c0 + (size_t)BB * HH,
                                      ping0, cn + (size_t)BB * HH, pooled);
  for (int t = 0; t < TT; ++t){
    const unsigned short* hp = (t & 1) ? ping1 : ping0;
    unsigned short*       ho = (t & 1) ? ping0 : ping1;
    lstm_step<1><<<64, 256, 0, stream>>>(y0 + (size_t)t * BB * HH, nullptr, hp, ho,
                                         Wih1_bf, Whh1_bf, cn + (size_t)BB * HH, pooled);
  }
  save_h<<<256, 256, 0, stream>>>(ping0, hn + (size_t)BB * HH);   // t=511 wrote ping0

  decode_k<<<64, 256, 0, stream>>>(pooled, decW, decb, out);
}

// Round 2
// 17805.569 us; speedup vs baseline: 1.9603x; 1.9603x over previous
//
#include <hip/hip_runtime.h>

#define TT 512
#define BB 64
#define HH 1024
#define EE 512
#define VV 50000
#define BBHH (BB*HH)
#define NBLK 256
#define BPL 128

typedef __attribute__((ext_vector_type(8))) short bf16x8;
typedef __attribute__((ext_vector_type(4))) float f32x4;

__device__ inline float b2f(unsigned short b){
  unsigned int u = ((unsigned int)b) << 16;
  float f; __builtin_memcpy(&f, &u, 4); return f;
}
__device__ inline unsigned short f2b(float f){
  unsigned int u; __builtin_memcpy(&u, &f, 4);
  unsigned int r = (u + 0x7FFFu + ((u >> 16) & 1u)) >> 16;
  return (unsigned short)r;
}
__device__ inline float sigmoidf_(float x){ return 1.0f / (1.0f + __expf(-x)); }
__device__ inline float tanhf_(float x){ float e = __expf(2.0f * x); return 1.0f - 2.0f / (e + 1.0f); }

__device__ inline bf16x8 pack8(float4 a, float4 b){
  bf16x8 r;
  r[0] = (short)f2b(a.x); r[1] = (short)f2b(a.y); r[2] = (short)f2b(a.z); r[3] = (short)f2b(a.w);
  r[4] = (short)f2b(b.x); r[5] = (short)f2b(b.y); r[6] = (short)f2b(b.z); r[7] = (short)f2b(b.w);
  return r;
}

// ---------------- cast fp32 -> bf16 ----------------
__global__ void cast_f2b(const float* __restrict__ src, unsigned short* __restrict__ dst, long n){
  long i = ((long)blockIdx.x * blockDim.x + threadIdx.x) * 4;
  long stride = (long)gridDim.x * blockDim.x * 4;
  for (; i + 3 < n; i += stride){
    float4 v = *reinterpret_cast<const float4*>(src + i);
    ushort4 r;
    r.x = f2b(v.x); r.y = f2b(v.y); r.z = f2b(v.z); r.w = f2b(v.w);
    *reinterpret_cast<ushort4*>(dst + i) = r;
  }
}

// ---------------- init: h0 (fp32 [2,B,H]) -> bf16 ping buffer 1 of each layer ----------------
__global__ void init_h(const float* __restrict__ h0,
                       unsigned short* __restrict__ hb0, unsigned short* __restrict__ hb1){
  int i = blockIdx.x * blockDim.x + threadIdx.x;   // 0..BBHH-1
  hb0[BBHH + i] = f2b(h0[i]);
  hb1[BBHH + i] = f2b(h0[BBHH + i]);
}

// ---------------- grid barrier (per-interval distinct counter; agent scope) ----------------
__device__ __forceinline__ void gbar(unsigned int* ctr){
  __syncthreads();
  if (threadIdx.x == 0){
    __hip_atomic_fetch_add(ctr, 1u, __ATOMIC_RELEASE, __HIP_MEMORY_SCOPE_AGENT);
    while (__hip_atomic_load(ctr, __ATOMIC_RELAXED, __HIP_MEMORY_SCOPE_AGENT) < (unsigned)NBLK)
      __builtin_amdgcn_s_sleep(1);
  }
  __syncthreads();
  __builtin_amdgcn_fence(__ATOMIC_ACQUIRE, "agent");
}

// ---------------- persistent 2-layer LSTM ----------------
// 256 blocks x 256 threads. Blocks 0..127 = layer0 (8 hidden units each),
// 128..255 = layer1. Each wave holds its K-quarter of the block's 32 gate rows
// as MFMA A-fragments in registers. Waves split K; LDS reduce; wave w owns
// batch tile w for the elementwise update. c-state, pooled-dot live in regs.
template<int LAYER>
__device__ __forceinline__ void run_layer(
    int bid_l,
    const int* __restrict__ inputs, const float* __restrict__ c0,
    const unsigned short* __restrict__ emb_bf,
    const float* __restrict__ Wx, const float* __restrict__ Wh,
    unsigned short* __restrict__ hb_self,   // this layer's ping-pong [2][BBHH]
    const unsigned short* __restrict__ hb_prev, // layer0's ping-pong (x source for L1)
    const float* __restrict__ decW, const float* __restrict__ decb,
    float* __restrict__ dec_out, float* __restrict__ hn, float* __restrict__ cn,
    unsigned int* __restrict__ bars, float* lds)
{
  constexpr int KX  = (LAYER == 0) ? EE : HH;
  constexpr int KT  = KX + HH;
  constexpr int KSL = KT / 4;       // per-wave K slice: 384 / 512
  constexpr int NKK = KSL / 32;     // 12 / 16

  const int tid  = threadIdx.x;
  const int lane = tid & 63;
  const int wid  = tid >> 6;
  const int l16  = lane & 15;
  const int kq   = ((lane >> 4) & 3) << 3;      // 0,8,16,24
  const int j0   = bid_l * 8;                   // hidden-unit base
  const int u_lo = lane >> 4;                   // 0..3
  const int bown = wid * 16 + l16;              // owned batch row

  // ---- preload weight fragments into registers: wfr[m][kk] ----
  bf16x8 wfr[2][NKK];
  #pragma unroll
  for (int m = 0; m < 2; ++m){
    #pragma unroll
    for (int kk = 0; kk < NKK; ++kk){
      int row  = m * 16 + l16;                  // 0..31, = u*4 + g
      int u    = row >> 2, g = row & 3;
      int grow = g * HH + j0 + u;
      int k0   = wid * KSL + kk * 32 + kq;
      const float* src = (k0 < KX) ? (Wx + (size_t)grow * KX + k0)
                                   : (Wh + (size_t)grow * HH + (k0 - KX));
      float4 a = *reinterpret_cast<const float4*>(src);
      float4 b = *reinterpret_cast<const float4*>(src + 4);
      wfr[m][kk] = pack8(a, b);
    }
  }

  // ---- per-lane cell state (2 units: j0+u_lo, j0+u_lo+4), pooled dot ----
  const float* c0l = c0 + (size_t)LAYER * BBHH;
  float cst0 = c0l[(size_t)bown * HH + j0 + u_lo];
  float cst1 = c0l[(size_t)bown * HH + j0 + u_lo + 4];
  float pooldec = 0.0f;
  float dwv0 = 0.0f, dwv1 = 0.0f;
  if (LAYER == 1){ dwv0 = decW[j0 + u_lo]; dwv1 = decW[j0 + u_lo + 4]; }

  for (int iv = 0; iv < TT + 1; ++iv){
    const bool active = (LAYER == 0) ? (iv < TT) : (iv >= 1);
    const int t = (LAYER == 0) ? iv : iv - 1;

    if (active){
      const unsigned short* hsrc = hb_self + (size_t)((t & 1) ^ 1) * BBHH;
      const unsigned short* xsrc = (LAYER == 1) ? (hb_prev + (size_t)(t & 1) * BBHH) : nullptr;

      // row base pointers for B-operand
      const unsigned short* xrow[4];
      const unsigned short* hrow[4];
      #pragma unroll
      for (int nt = 0; nt < 4; ++nt){
        int b = nt * 16 + l16;
        if (LAYER == 0){
          int idx = inputs[t * BB + b];
          xrow[nt] = emb_bf + (size_t)idx * EE;
        } else {
          xrow[nt] = xsrc + (size_t)b * HH;
        }
        hrow[nt] = hsrc + (size_t)b * HH;
      }

      f32x4 acc[2][4];
      #pragma unroll
      for (int m = 0; m < 2; ++m)
        #pragma unroll
        for (int nt = 0; nt < 4; ++nt)
          acc[m][nt] = (f32x4){0.f,0.f,0.f,0.f};

      #pragma unroll
      for (int kk = 0; kk < NKK; ++kk){
        const int kbase = wid * KSL + kk * 32;       // wave-uniform
        #pragma unroll
        for (int nt = 0; nt < 4; ++nt){
          const unsigned short* bp = (kbase < KX) ? (xrow[nt] + kbase + kq)
                                                  : (hrow[nt] + (kbase - KX) + kq);
          bf16x8 bfrag = *reinterpret_cast<const bf16x8*>(bp);
          acc[0][nt] = __builtin_amdgcn_mfma_f32_16x16x32_bf16(wfr[0][kk], bfrag, acc[0][nt], 0, 0, 0);
          acc[1][nt] = __builtin_amdgcn_mfma_f32_16x16x32_bf16(wfr[1][kk], bfrag, acc[1][nt], 0, 0, 0);
        }
      }

      // ---- cross-wave K reduction via LDS ----
      #pragma unroll
      for (int nt = 0; nt < 4; ++nt)
        #pragma unroll
        for (int m = 0; m < 2; ++m)
          *reinterpret_cast<f32x4*>(&lds[(((nt * 4 + wid) * 64 + lane) << 3) + m * 4]) = acc[m][nt];
      __syncthreads();
      f32x4 s0 = (f32x4){0.f,0.f,0.f,0.f};
      f32x4 s1 = (f32x4){0.f,0.f,0.f,0.f};
      #pragma unroll
      for (int w = 0; w < 4; ++w){
        s0 += *reinterpret_cast<f32x4*>(&lds[(((wid * 4 + w) * 64 + lane) << 3) + 0]);
        s1 += *reinterpret_cast<f32x4*>(&lds[(((wid * 4 + w) * 64 + lane) << 3) + 4]);
      }

      // ---- elementwise cell update for owned (batch=bown, units j0+u_lo, +4) ----
      float gi0 = sigmoidf_(s0[0]);
      float gf0 = sigmoidf_(s0[1]);
      float gg0 = tanhf_(s0[2]);
      float go0 = sigmoidf_(s0[3]);
      cst0 = gf0 * cst0 + gi0 * gg0;
      float hv0 = go0 * tanhf_(cst0);

      float gi1 = sigmoidf_(s1[0]);
      float gf1 = sigmoidf_(s1[1]);
      float gg1 = tanhf_(s1[2]);
      float go1 = sigmoidf_(s1[3]);
      cst1 = gf1 * cst1 + gi1 * gg1;
      float hv1 = go1 * tanhf_(cst1);

      unsigned short* hdst = hb_self + (size_t)(t & 1) * BBHH;
      size_t o0 = (size_t)bown * HH + j0 + u_lo;
      hdst[o0]     = f2b(hv0);
      hdst[o0 + 4] = f2b(hv1);

      if (LAYER == 1) pooldec += hv0 * dwv0 + hv1 * dwv1;

      if (t == TT - 1){
        float* hnl = hn + (size_t)LAYER * BBHH;
        float* cnl = cn + (size_t)LAYER * BBHH;
        hnl[o0] = hv0; hnl[o0 + 4] = hv1;
        cnl[o0] = cst0; cnl[o0 + 4] = cst1;
      }
    }

    if (iv < TT) gbar(bars + iv);
  }

  if (LAYER == 1){
    float contrib = pooldec * (1.0f / (float)TT);
    if (j0 == 0 && u_lo == 0) contrib += decb[0];   // exactly one lane per batch adds bias
    atomicAdd(&dec_out[bown], contrib);
  }
}

__global__ __launch_bounds__(256, 1) void lstm_persist(
    const int* __restrict__ inputs, const float* __restrict__ c0,
    const unsigned short* __restrict__ emb_bf,
    const float* __restrict__ Wih0, const float* __restrict__ Whh0,
    const float* __restrict__ Wih1, const float* __restrict__ Whh1,
    const float* __restrict__ decW, const float* __restrict__ decb,
    unsigned short* __restrict__ hb0, unsigned short* __restrict__ hb1,
    float* __restrict__ dec_out, float* __restrict__ hn, float* __restrict__ cn,
    unsigned int* __restrict__ bars)
{
  __shared__ float lds[4 * 4 * 64 * 8];   // 32 KB reduce buffer
  int bid = blockIdx.x;
  if (bid < BPL){
    run_layer<0>(bid, inputs, c0, emb_bf, Wih0, Whh0,
                 hb0, nullptr, decW, decb, dec_out, hn, cn, bars, lds);
  } else {
    run_layer<1>(bid - BPL, inputs, c0, emb_bf, Wih1, Whh1,
                 hb1, hb0, decW, decb, dec_out, hn, cn, bars, lds);
  }
}

extern "C" void kernel_launch(void* const* d_in, const int* in_sizes, int n_in,
                              void* d_out, int out_size, void* d_ws, size_t ws_size,
                              hipStream_t stream){
  const int*   inputs = (const int*)d_in[0];
  const float* c0     = (const float*)d_in[2];
  const float* h0     = (const float*)d_in[1];
  const float* emb    = (const float*)d_in[3];
  const float* Wih0   = (const float*)d_in[4];
  const float* Whh0   = (const float*)d_in[5];
  const float* Wih1   = (const float*)d_in[6];
  const float* Whh1   = (const float*)d_in[7];
  const float* decW   = (const float*)d_in[8];
  const float* decb   = (const float*)d_in[9];

  char* ws = (char*)d_ws;
  size_t off = 0;
  auto alloc = [&](size_t bytes) -> void* {
    void* p = ws + off;
    off += (bytes + 255) & ~(size_t)255;
    return p;
  };
  unsigned short* emb_bf = (unsigned short*)alloc((size_t)VV * EE * 2);
  unsigned short* hb0    = (unsigned short*)alloc((size_t)2 * BBHH * 2);
  unsigned short* hb1    = (unsigned short*)alloc((size_t)2 * BBHH * 2);
  unsigned int*   bars   = (unsigned int*)alloc((size_t)520 * 4);

  float* out = (float*)d_out;            // decoded [B]
  float* hn  = out + BB;                 // [2,B,H]
  float* cn  = out + BB + 2 * BBHH;      // [2,B,H]

  hipMemsetAsync(bars, 0, 520 * 4, stream);
  hipMemsetAsync(out, 0, BB * 4, stream);

  cast_f2b<<<2048, 256, 0, stream>>>(emb, emb_bf, (long)VV * EE);
  init_h<<<BBHH / 256, 256, 0, stream>>>(h0, hb0, hb1);

  lstm_persist<<<NBLK, 256, 0, stream>>>(inputs, c0, emb_bf,
                                         Wih0, Whh0, Wih1, Whh1, decW, decb,
                                         hb0, hb1, out, hn, cn, bars);
}

// Round 3
// 5580.079 us; speedup vs baseline: 6.2550x; 3.1909x over previous
//
#include <hip/hip_runtime.h>

#define TT 512
#define BB 64
#define HH 1024
#define EE 512
#define VV 50000
#define BBHH (BB*HH)
#define BPL 128
#define NBLK 256
#define NSUB 4

typedef __attribute__((ext_vector_type(8))) short bf16x8;
typedef __attribute__((ext_vector_type(4))) float f32x4;

__device__ inline float b2f(unsigned short b){
  unsigned int u = ((unsigned int)b) << 16;
  float f; __builtin_memcpy(&f, &u, 4); return f;
}
__device__ inline unsigned short f2b(float f){
  unsigned int u; __builtin_memcpy(&u, &f, 4);
  unsigned int r = (u + 0x7FFFu + ((u >> 16) & 1u)) >> 16;
  return (unsigned short)r;
}
__device__ inline float sigmoidf_(float x){ return 1.0f / (1.0f + __expf(-x)); }
__device__ inline float tanhf_(float x){ float e = __expf(2.0f * x); return 1.0f - 2.0f / (e + 1.0f); }

__device__ inline bf16x8 pack8(float4 a, float4 b){
  bf16x8 r;
  r[0] = (short)f2b(a.x); r[1] = (short)f2b(a.y); r[2] = (short)f2b(a.z); r[3] = (short)f2b(a.w);
  r[4] = (short)f2b(b.x); r[5] = (short)f2b(b.y); r[6] = (short)f2b(b.z); r[7] = (short)f2b(b.w);
  return r;
}

// ---------------- cast fp32 -> bf16 ----------------
__global__ void cast_f2b(const float* __restrict__ src, unsigned short* __restrict__ dst, long n){
  long i = ((long)blockIdx.x * blockDim.x + threadIdx.x) * 4;
  long stride = (long)gridDim.x * blockDim.x * 4;
  for (; i + 3 < n; i += stride){
    float4 v = *reinterpret_cast<const float4*>(src + i);
    ushort4 r;
    r.x = f2b(v.x); r.y = f2b(v.y); r.z = f2b(v.z); r.w = f2b(v.w);
    *reinterpret_cast<ushort4*>(dst + i) = r;
  }
}

// ---------------- init: h0 fp32 [2,B,H] -> per-layer bf16 init rows ----------------
__global__ void init_h(const float* __restrict__ h0,
                       unsigned short* __restrict__ h0i, unsigned short* __restrict__ h1i){
  int i = blockIdx.x * blockDim.x + threadIdx.x;   // 0..BBHH-1
  h0i[i] = f2b(h0[i]);
  h1i[i] = f2b(h0[BBHH + i]);
}

// ---------------- layer-wide counter wait / arrive (no cache maintenance!) ----------------
// 4 sub-counters per (layer, t), each on its own 128B line. Relaxed agent atomics
// only -> global_atomic/sc1 loads, no buffer_wbl2 / buffer_inv.
__device__ __forceinline__ void wait128(unsigned* c){
  if (threadIdx.x == 0){
    for (;;){
      unsigned s = __hip_atomic_load(c +  0, __ATOMIC_RELAXED, __HIP_MEMORY_SCOPE_AGENT)
                 + __hip_atomic_load(c + 32, __ATOMIC_RELAXED, __HIP_MEMORY_SCOPE_AGENT)
                 + __hip_atomic_load(c + 64, __ATOMIC_RELAXED, __HIP_MEMORY_SCOPE_AGENT)
                 + __hip_atomic_load(c + 96, __ATOMIC_RELAXED, __HIP_MEMORY_SCOPE_AGENT);
      if (s >= (unsigned)BPL) break;
      __builtin_amdgcn_s_sleep(8);
    }
  }
  __syncthreads();
}

__device__ __forceinline__ void arrive(unsigned* c, int sub){
  // every wave drains its own sc1 h-stores to the coherence point first
  asm volatile("s_waitcnt vmcnt(0)" ::: "memory");
  __syncthreads();
  if (threadIdx.x == 0)
    __hip_atomic_fetch_add(c + sub * 32, 1u, __ATOMIC_RELAXED, __HIP_MEMORY_SCOPE_AGENT);
}

// ---------------- persistent layer loop ----------------
// 128 blocks per layer, 8 hidden units per block, 4 waves split K.
// Gate-row -> (unit,gate) mapping chosen so each lane owns ADJACENT units
// (u = 2*(r>>2) + m, g = r&3): packed 4B h-store, float2 hn/cn stores.
template<int LAYER>
__device__ void run_layer(
    int bid_l,
    const int* __restrict__ inputs, const float* __restrict__ c0,
    const unsigned short* __restrict__ emb_bf,
    const float* __restrict__ Wx, const float* __restrict__ Wh,
    const unsigned short* __restrict__ hinit,   // [B,H] bf16 (this layer's h at t=-1)
    unsigned short* __restrict__ hist_self,     // [T,B,H] bf16 rotating h history
    const unsigned short* __restrict__ hist_x,  // L1: y0 history; L0: unused
    const float* __restrict__ decW, const float* __restrict__ decb,
    float* __restrict__ dec_out, float* __restrict__ hn, float* __restrict__ cn,
    unsigned* __restrict__ ctr0, unsigned* __restrict__ ctr1,
    float* lds)
{
  constexpr int KX  = (LAYER == 0) ? EE : HH;
  constexpr int NKX = KX / 128;                 // per-wave x kk-iters: 4 / 8
  constexpr int NKH = 8;                        // per-wave h kk-iters (HH/4/32)

  const int tid  = threadIdx.x;
  const int lane = tid & 63;
  const int wid  = tid >> 6;
  const int l16  = lane & 15;
  const int hi   = lane >> 4;                   // 0..3
  const int kq   = hi << 3;                     // 0,8,16,24
  const int j0   = bid_l * 8;
  const int sub  = bid_l & 3;
  const int bown = wid * 16 + l16;              // owned batch row (reduce phase)

  // ---- weight preload into registers ----
  bf16x8 wx[2][NKX], wh[2][NKH];
  #pragma unroll
  for (int m = 0; m < 2; ++m){
    int g = l16 & 3;
    int u = 2 * (l16 >> 2) + m;
    const float* rx = Wx + (size_t)(g * HH + j0 + u) * KX;
    const float* rh = Wh + (size_t)(g * HH + j0 + u) * HH;
    #pragma unroll
    for (int kk = 0; kk < NKX; ++kk){
      int k0 = wid * (KX / 4) + kk * 32 + kq;
      wx[m][kk] = pack8(*reinterpret_cast<const float4*>(rx + k0),
                        *reinterpret_cast<const float4*>(rx + k0 + 4));
    }
    #pragma unroll
    for (int kk = 0; kk < NKH; ++kk){
      int k0 = wid * 256 + kk * 32 + kq;
      wh[m][kk] = pack8(*reinterpret_cast<const float4*>(rh + k0),
                        *reinterpret_cast<const float4*>(rh + k0 + 4));
    }
  }

  // ---- per-lane cell state: units j0+2*hi, j0+2*hi+1 of batch bown ----
  const float* c0l = c0 + (size_t)LAYER * BBHH;
  float cst0 = c0l[(size_t)bown * HH + j0 + 2 * hi];
  float cst1 = c0l[(size_t)bown * HH + j0 + 2 * hi + 1];
  float pooldec = 0.0f, dwv0 = 0.0f, dwv1 = 0.0f;
  if (LAYER == 1){ dwv0 = decW[j0 + 2 * hi]; dwv1 = decW[j0 + 2 * hi + 1]; }

  for (int t = 0; t < TT; ++t){
    f32x4 acc[2][4];
    #pragma unroll
    for (int m = 0; m < 2; ++m)
      #pragma unroll
      for (int nt = 0; nt < 4; ++nt)
        acc[m][nt] = (f32x4){0.f,0.f,0.f,0.f};

    // ---------- x-part ----------
    const unsigned short* xrow[4];
    if (LAYER == 0){
      #pragma unroll
      for (int nt = 0; nt < 4; ++nt)
        xrow[nt] = emb_bf + (size_t)inputs[t * BB + nt * 16 + l16] * EE;
    } else {
      wait128(ctr0 + t * (NSUB * 32));          // y0[t] published by layer 0
      const unsigned short* xs = hist_x + (size_t)t * BBHH;
      #pragma unroll
      for (int nt = 0; nt < 4; ++nt)
        xrow[nt] = xs + (size_t)(nt * 16 + l16) * HH;
    }
    #pragma unroll
    for (int kk = 0; kk < NKX; ++kk){
      const int kb = wid * (KX / 4) + kk * 32 + kq;
      #pragma unroll
      for (int nt = 0; nt < 4; ++nt){
        bf16x8 bfrag = *reinterpret_cast<const bf16x8*>(xrow[nt] + kb);
        acc[0][nt] = __builtin_amdgcn_mfma_f32_16x16x32_bf16(wx[0][kk], bfrag, acc[0][nt], 0, 0, 0);
        acc[1][nt] = __builtin_amdgcn_mfma_f32_16x16x32_bf16(wx[1][kk], bfrag, acc[1][nt], 0, 0, 0);
      }
    }

    // ---------- own-layer h dependency ----------
    if (t > 0){
      if (LAYER == 0) wait128(ctr0 + (t - 1) * (NSUB * 32));
      else            wait128(ctr1 + (t - 1) * (NSUB * 32));
    }
    const unsigned short* hsrc = (t == 0) ? hinit : hist_self + (size_t)(t - 1) * BBHH;
    const unsigned short* hrow[4];
    #pragma unroll
    for (int nt = 0; nt < 4; ++nt)
      hrow[nt] = hsrc + (size_t)(nt * 16 + l16) * HH;
    #pragma unroll
    for (int kk = 0; kk < NKH; ++kk){
      const int kb = wid * 256 + kk * 32 + kq;
      #pragma unroll
      for (int nt = 0; nt < 4; ++nt){
        bf16x8 bfrag = *reinterpret_cast<const bf16x8*>(hrow[nt] + kb);
        acc[0][nt] = __builtin_amdgcn_mfma_f32_16x16x32_bf16(wh[0][kk], bfrag, acc[0][nt], 0, 0, 0);
        acc[1][nt] = __builtin_amdgcn_mfma_f32_16x16x32_bf16(wh[1][kk], bfrag, acc[1][nt], 0, 0, 0);
      }
    }

    // ---------- cross-wave K reduction via LDS ----------
    #pragma unroll
    for (int nt = 0; nt < 4; ++nt)
      #pragma unroll
      for (int m = 0; m < 2; ++m)
        *reinterpret_cast<f32x4*>(&lds[(((nt * 4 + wid) * 64 + lane) << 3) + m * 4]) = acc[m][nt];
    __syncthreads();
    f32x4 s0 = (f32x4){0.f,0.f,0.f,0.f};
    f32x4 s1 = (f32x4){0.f,0.f,0.f,0.f};
    #pragma unroll
    for (int w = 0; w < 4; ++w){
      s0 += *reinterpret_cast<f32x4*>(&lds[(((wid * 4 + w) * 64 + lane) << 3) + 0]);
      s1 += *reinterpret_cast<f32x4*>(&lds[(((wid * 4 + w) * 64 + lane) << 3) + 4]);
    }

    // ---------- cell update ----------
    float gi0 = sigmoidf_(s0[0]), gf0 = sigmoidf_(s0[1]);
    float gg0 = tanhf_(s0[2]),    go0 = sigmoidf_(s0[3]);
    cst0 = gf0 * cst0 + gi0 * gg0;
    float hv0 = go0 * tanhf_(cst0);

    float gi1 = sigmoidf_(s1[0]), gf1 = sigmoidf_(s1[1]);
    float gg1 = tanhf_(s1[2]),    go1 = sigmoidf_(s1[3]);
    cst1 = gf1 * cst1 + gi1 * gg1;
    float hv1 = go1 * tanhf_(cst1);

    // publish h: packed 4B write-through (sc1) store, no L2 dirty lines
    unsigned hword = (unsigned)f2b(hv0) | ((unsigned)f2b(hv1) << 16);
    unsigned* hp = (unsigned*)(hist_self + (size_t)t * BBHH + (size_t)bown * HH + j0 + 2 * hi);
    __hip_atomic_store(hp, hword, __ATOMIC_RELAXED, __HIP_MEMORY_SCOPE_AGENT);

    if (LAYER == 1) pooldec += hv0 * dwv0 + hv1 * dwv1;

    if (t == TT - 1){
      size_t o = (size_t)LAYER * BBHH + (size_t)bown * HH + j0 + 2 * hi;
      *reinterpret_cast<float2*>(hn + o) = make_float2(hv0, hv1);
      *reinterpret_cast<float2*>(cn + o) = make_float2(cst0, cst1);
    }

    arrive((LAYER == 0 ? ctr0 : ctr1) + t * (NSUB * 32), sub);
  }

  // ---------- decode contribution ----------
  if (LAYER == 1){
    pooldec += __shfl_xor(pooldec, 16);
    pooldec += __shfl_xor(pooldec, 32);
    if (hi == 0){
      float contrib = pooldec * (1.0f / (float)TT);
      if (bid_l == 0) contrib += decb[0];        // once per batch element
      atomicAdd(&dec_out[bown], contrib);
    }
  }
}

__global__ __launch_bounds__(256, 1) void lstm_persist(
    const int* __restrict__ inputs, const float* __restrict__ c0,
    const unsigned short* __restrict__ emb_bf,
    const float* __restrict__ Wih0, const float* __restrict__ Whh0,
    const float* __restrict__ Wih1, const float* __restrict__ Whh1,
    const unsigned short* __restrict__ h0i, const unsigned short* __restrict__ h1i,
    unsigned short* __restrict__ y0, unsigned short* __restrict__ h1buf,
    const float* __restrict__ decW, const float* __restrict__ decb,
    float* __restrict__ dec_out, float* __restrict__ hn, float* __restrict__ cn,
    unsigned* __restrict__ ctr)
{
  __shared__ float lds[4 * 4 * 64 * 8];   // 32 KB
  unsigned* ctr0 = ctr;
  unsigned* ctr1 = ctr + TT * (NSUB * 32);
  int bid = blockIdx.x;
  if (bid < BPL){
    run_layer<0>(bid, inputs, c0, emb_bf, Wih0, Whh0, h0i, y0, nullptr,
                 decW, decb, dec_out, hn, cn, ctr0, ctr1, lds);
  } else {
    run_layer<1>(bid - BPL, inputs, c0, emb_bf, Wih1, Whh1, h1i, h1buf, y0,
                 decW, decb, dec_out, hn, cn, ctr0, ctr1, lds);
  }
}

extern "C" void kernel_launch(void* const* d_in, const int* in_sizes, int n_in,
                              void* d_out, int out_size, void* d_ws, size_t ws_size,
                              hipStream_t stream){
  const int*   inputs = (const int*)d_in[0];
  const float* h0     = (const float*)d_in[1];
  const float* c0     = (const float*)d_in[2];
  const float* emb    = (const float*)d_in[3];
  const float* Wih0   = (const float*)d_in[4];
  const float* Whh0   = (const float*)d_in[5];
  const float* Wih1   = (const float*)d_in[6];
  const float* Whh1   = (const float*)d_in[7];
  const float* decW   = (const float*)d_in[8];
  const float* decb   = (const float*)d_in[9];

  char* ws = (char*)d_ws;
  size_t off = 0;
  auto alloc = [&](size_t bytes) -> void* {
    void* p = ws + off;
    off += (bytes + 255) & ~(size_t)255;
    return p;
  };
  unsigned short* emb_bf = (unsigned short*)alloc((size_t)VV * EE * 2);        // 51.2 MB
  unsigned short* y0     = (unsigned short*)alloc((size_t)TT * BBHH * 2);      // 64 MB
  unsigned short* h1buf  = (unsigned short*)alloc((size_t)TT * BBHH * 2);      // 64 MB
  unsigned short* h0i    = (unsigned short*)alloc((size_t)BBHH * 2);
  unsigned short* h1i    = (unsigned short*)alloc((size_t)BBHH * 2);
  unsigned int*   ctr    = (unsigned int*)alloc((size_t)2 * TT * NSUB * 32 * 4); // 512 KB

  float* out = (float*)d_out;            // decoded [B]
  float* hn  = out + BB;                 // [2,B,H]
  float* cn  = out + BB + 2 * BBHH;      // [2,B,H]

  hipMemsetAsync(ctr, 0, (size_t)2 * TT * NSUB * 32 * 4, stream);
  hipMemsetAsync(out, 0, BB * 4, stream);

  cast_f2b<<<2048, 256, 0, stream>>>(emb, emb_bf, (long)VV * EE);
  init_h<<<BBHH / 256, 256, 0, stream>>>(h0, h0i, h1i);

  lstm_persist<<<NBLK, 256, 0, stream>>>(inputs, c0, emb_bf,
                                         Wih0, Whh0, Wih1, Whh1,
                                         h0i, h1i, y0, h1buf,
                                         decW, decb, out, hn, cn, ctr);
}